// Round 7
// baseline (181.781 us; speedup 1.0000x reference)
//
#include <hip/hip_runtime.h>

// Segmented CRF forward (OneCrfCCKSDecoder), exp-domain, R7.
// T=128, B=512, E=128, EVENTLEN=8, NEG=-10000.
//
// R6 post-mortem: renorm off-chain was NEUTRAL -> chain = dot->write->
// lgkm->read->dot with ~1260cyc/step of SIMD-idle stall; 512 waves on 1024
// SIMDs = 1 wave/SIMD = zero latency hiding. R7: pack 8 waves (8 independent
// batches) per 512-thread wg, grid=64 -> 2 waves/SIMD. Wave A's stall cycles
// are filled by wave B's issue. No cross-wave sync: per-wave private hbuf
// slice, lgkmcnt-only fence. __launch_bounds__(512,2) caps regs at 256/wave
// (measured need ~212 incl AGPR E-table) so 2 waves/SIMD actually fit.
//
// Numerics identical to R6 (validated absmax 0.0): stale renorm
// 1/(16*max(u_prev)) folded into h, M += log bookkeeping exact; h f16-safe;
// row 0 of exp(T) and te[127] exactly 0 (matches fp32 exp(-10000)=0).

typedef _Float16 h2_t __attribute__((ext_vector_type(2)));
typedef _Float16 h8_t __attribute__((ext_vector_type(8)));

#define NEG_VAL (-10000.0f)
#define LOG16   2.7725887222397812f

#if __has_builtin(__builtin_amdgcn_fdot2)
#define FDOT2(a, b, c) __builtin_amdgcn_fdot2((a), (b), (c), false)
#else
static __device__ __forceinline__ float FDOT2(h2_t a, h2_t b, float c) {
    return c + (float)a[0] * (float)b[0] + (float)a[1] * (float)b[1];
}
#endif

// LDS-ordering-only fence (per-wave counter, wave-private buffer):
// does NOT drain vmcnt, feat prefetch stays in flight.
#define LDS_FENCE() asm volatile("s_waitcnt lgkmcnt(0)" ::: "memory")

// ---- DPP wave-64 reductions (VALU pipe; validated R4-R6) ----
template <int CTRL, int RMASK>
static __device__ __forceinline__ float dpp_ident(float old_, float src) {
    return __builtin_bit_cast(float, __builtin_amdgcn_update_dpp(
        __builtin_bit_cast(int, old_), __builtin_bit_cast(int, src),
        CTRL, RMASK, 0xf, false));
}

static __device__ __forceinline__ float wave_max_dpp(float v) {
    v = fmaxf(v, dpp_ident<0x111, 0xf>(v, v));   // row_shr:1
    v = fmaxf(v, dpp_ident<0x112, 0xf>(v, v));   // row_shr:2
    v = fmaxf(v, dpp_ident<0x114, 0xf>(v, v));   // row_shr:4
    v = fmaxf(v, dpp_ident<0x118, 0xf>(v, v));   // row_shr:8
    v = fmaxf(v, dpp_ident<0x142, 0xa>(v, v));   // row_bcast:15 -> rows 1,3
    v = fmaxf(v, dpp_ident<0x143, 0xc>(v, v));   // row_bcast:31 -> rows 2,3
    return __builtin_bit_cast(float,
        __builtin_amdgcn_readlane(__builtin_bit_cast(int, v), 63));
}

static __device__ __forceinline__ float wave_sum_dpp(float v) {
    v = v + dpp_ident<0x111, 0xf>(0.0f, v);
    v = v + dpp_ident<0x112, 0xf>(0.0f, v);
    v = v + dpp_ident<0x114, 0xf>(0.0f, v);
    v = v + dpp_ident<0x118, 0xf>(0.0f, v);
    v = v + dpp_ident<0x142, 0xa>(0.0f, v);
    v = v + dpp_ident<0x143, 0xc>(0.0f, v);
    return __builtin_bit_cast(float,
        __builtin_amdgcn_readlane(__builtin_bit_cast(int, v), 63));
}

__global__ __launch_bounds__(512, 2)   // 8 waves/wg, 2 waves/SIMD, <=256 reg
void crf_fwd(const float* __restrict__ feats,   // [128][512][128]
             const float* __restrict__ trans,   // [128][128]
             float* __restrict__ out)
{
    const int tid = threadIdx.x;
    const int wid = tid >> 6;          // wave in wg: 0..7
    const int L   = tid & 63;          // lane
    const int b   = blockIdx.x * 8 + wid;   // one batch per wave
    const int j0  = 2 * L;
    const int j1  = 2 * L + 1;

    // exp(trans) rows j0, j1, f16-packed over k: 128 regs (AGPR-backed).
    h2_t E0[64], E1[64];
    {
        const float4* r0 = (const float4*)(trans + (size_t)j0 * 128);
        const float4* r1 = (const float4*)(trans + (size_t)j1 * 128);
        #pragma unroll
        for (int i = 0; i < 32; ++i) {
            float4 a = r0[i];
            float4 c = r1[i];
            h2_t p;
            p[0] = (_Float16)__expf(a.x); p[1] = (_Float16)__expf(a.y); E0[2*i]   = p;
            p[0] = (_Float16)__expf(a.z); p[1] = (_Float16)__expf(a.w); E0[2*i+1] = p;
            p[0] = (_Float16)__expf(c.x); p[1] = (_Float16)__expf(c.y); E1[2*i]   = p;
            p[0] = (_Float16)__expf(c.z); p[1] = (_Float16)__expf(c.w); E1[2*i+1] = p;
        }
    }
    const float te0 = __expf(trans[127 * 128 + j0]);  // exp(T[127, j0])
    const float te1 = __expf(trans[127 * 128 + j1]);

    // per-WAVE private h slice: no cross-wave sync ever needed.
    __shared__ __align__(16) h2_t hbuf[8][64];
    h2_t* hmine = hbuf[wid];

    // feat pair [t][b][2L..2L+1]; per-t stride 65536 floats = 32768 float2
    const float2* fb = (const float2*)(feats + (size_t)b * 128 + 2 * L);
    #define FSTR 32768

    // feat pipeline: ef = exp(feat[t]); r1v/r2v = raw feat[t+1]/[t+2]
    float2 l1  = fb[1 * FSTR];
    float2 r1v = fb[2 * FSTR];
    float2 r2v = fb[3 * FSTR];
    float ef0 = __expf(l1.x), ef1 = __expf(l1.y);

    float u0 = 1.0f, u1 = 1.0f;
    float M     = (b == 0) ? 0.0f : NEG_VAL;  // init_fv zeroes only batch-0 row
    float alpha = 0.0f;

    // stale-renorm pipeline (R6-validated): scale applied this step + its log
    float inv_apply  = 0.0625f;
    float logc_apply = LOG16;

    #pragma unroll 8
    for (int t = 1; t < 128; ++t) {
        const bool upd = (t & 7) != 0;

        if (upd) {
            // publish h = u * ef * inv_apply (stale scale, f16-safe)
            M += logc_apply;             // exact bookkeeping of applied scale
            h2_t hh;
            hh[0] = (_Float16)(u0 * (ef0 * inv_apply));
            hh[1] = (_Float16)(u1 * (ef1 * inv_apply));
            hmine[L] = hh;
            LDS_FENCE();                 // order write -> broadcast reads
        }

        // rotate feat pipeline (global loads stay in flight; no vmcnt drain)
        float2 nf = {0.0f, 0.0f};
        if (t + 3 < 128) nf = fb[(size_t)(t + 3) * FSTR];
        const float en0 = __expf(r1v.x), en1 = __expf(r1v.y);  // exp(feat[t+1])
        r1v = r2v; r2v = nf;

        if (upd) {
            // shadow work: next step's scale from CURRENT u (= s_{t-1});
            // independent of the dot, overlaps LDS latency + issue.
            float c = wave_max_dpp(fmaxf(u0, u1));
            float inv_next  = __builtin_amdgcn_rcpf(c) * 0.0625f;
            float logc_next = __logf(c) + LOG16;

            // ---- DP update: s[j] = sum_k h[k] * E[j,k] ----
            const h8_t* hv = (const h8_t*)hmine;
            float a0 = 0.f, b0 = 0.f;    // two chains for j0
            float a1 = 0.f, b1 = 0.f;    // two chains for j1
            #pragma unroll
            for (int i = 0; i < 16; ++i) {
                h8_t v = hv[i];          // wave-uniform broadcast, 8 h values
                h2_t p0; p0[0] = v[0]; p0[1] = v[1];
                h2_t p1; p1[0] = v[2]; p1[1] = v[3];
                h2_t p2; p2[0] = v[4]; p2[1] = v[5];
                h2_t p3; p3[0] = v[6]; p3[1] = v[7];
                a0 = FDOT2(E0[4*i + 0], p0, a0);
                b0 = FDOT2(E0[4*i + 1], p1, b0);
                a0 = FDOT2(E0[4*i + 2], p2, a0);
                b0 = FDOT2(E0[4*i + 3], p3, b0);
                a1 = FDOT2(E1[4*i + 0], p0, a1);
                b1 = FDOT2(E1[4*i + 1], p1, b1);
                a1 = FDOT2(E1[4*i + 2], p2, a1);
                b1 = FDOT2(E1[4*i + 3], p3, b1);
            }
            u0 = a0 + b0;                // raw (scale folded into h; M exact)
            u1 = a1 + b1;

            inv_apply  = inv_next;
            logc_apply = logc_next;
        } else {
            // ---- event boundary: alpha += M + log(sum_j u[j]*te[j]) ----
            float r = wave_sum_dpp(u0 * te0 + u1 * te1);
            alpha += M + __logf(r);      // wave-uniform
        }

        ef0 = en0; ef1 = en1;
    }

    // terminal accumulation
    {
        float r = wave_sum_dpp(u0 * te0 + u1 * te1);
        alpha += M + __logf(r);
    }

    if (L == 0)
        atomicAdd(out, alpha * (1.0f / (512.0f * 16.0f)));
}

extern "C" void kernel_launch(void* const* d_in, const int* in_sizes, int n_in,
                              void* d_out, int out_size, void* d_ws, size_t ws_size,
                              hipStream_t stream) {
    const float* feats = (const float*)d_in[0];   // [128,512,128] f32
    const float* trans = (const float*)d_in[1];   // [128,128] f32
    float* out = (float*)d_out;                   // scalar f32

    hipMemsetAsync(out, 0, sizeof(float), stream);
    crf_fwd<<<64, 512, 0, stream>>>(feats, trans, out);
}